// Round 7
// baseline (114.423 us; speedup 1.0000x reference)
//
#include <hip/hip_runtime.h>

// Problem constants: B=16384, IN_DIM=1024, D=256, C=100
#define BATCH 16384
#define KDIM  1024
#define DDIM  256
#define CNUM  100
#define CPAD  112
#define RSTR  36   // Rs row stride (floats): mult of 4 for b128 alignment

typedef __bf16 bf16x8 __attribute__((ext_vector_type(8)));
typedef float  floatx4 __attribute__((ext_vector_type(4)));

static __device__ __forceinline__ unsigned short f2b(float f) {
    return __builtin_bit_cast(unsigned short, (__bf16)f);
}

// ---------------- prep: W -> frag-major bf16 Wt2, P->bf16 + pnorm2 ----------
// Wt2 layout: element (n, k) with nblk=n>>4, lm=n&15, kblk=k>>5, lq=(k>>3)&3,
// j=k&7 lives at Wt2[(nblk*32 + kblk)*512 + (lq*16+lm)*8 + j].
__global__ __launch_bounds__(256) void prep(const float* __restrict__ W,
                                            const float* __restrict__ P,
                                            unsigned short* __restrict__ Wt2,
                                            unsigned short* __restrict__ Pbf,
                                            float* __restrict__ pnorm2) {
    __shared__ float T[32][33];
    const int bid = blockIdx.x;
    if (bid < 256) {
        const int k0 = (bid & 31) * 32;
        const int n0 = (bid >> 5) * 32;
        const int j  = threadIdx.x & 31;
        const int i0 = threadIdx.x >> 5;
#pragma unroll
        for (int l = 0; l < 4; ++l) {
            int i = i0 + l * 8;
            T[i][j] = W[(k0 + i) * DDIM + n0 + j];   // T[k-local][n-local]
        }
        __syncthreads();
        if (threadIdx.x < 128) {
            const int l  = threadIdx.x & 63;
            const int fn = threadIdx.x >> 6;
            const int lm = l & 15, lq = l >> 4;
            bf16x8 v;
#pragma unroll
            for (int jj = 0; jj < 8; ++jj)
                v[jj] = (__bf16)T[lq * 8 + jj][fn * 16 + lm];
            const int nblk = (n0 >> 4) + fn;
            const int kblk = k0 >> 5;
            *(bf16x8*)&Wt2[(nblk * 32 + kblk) * 512 + l * 8] = v;
        }
    } else {
        const int wave = threadIdx.x >> 6;
        const int lane = threadIdx.x & 63;
        const int c = (bid - 256) * 4 + wave;
        float s = 0.f;
#pragma unroll
        for (int jj = 0; jj < 4; ++jj) {
            int d = jj * 64 + lane;
            float v = (c < CNUM) ? P[c * DDIM + d] : 0.f;
            Pbf[c * DDIM + d] = f2b(v);
            s += v * v;
        }
#pragma unroll
        for (int m = 1; m < 64; m <<= 1) s += __shfl_xor(s, m, 64);
        if (lane == 0) pnorm2[c] = s;
    }
}

// ---------------- fused main -------------------------------------------------
// BM=32, SPLIT-K-2, 512 thr / 8 waves, grid 512 -> TWO blocks per CU =
// 4 waves/SIMD (requires VGPR<=128: acc[2][4]=32 regs makes this feasible;
// __launch_bounds__(512,4) caps the allocator). Traffic identical to round 6
// (B 134MB L2 total / 512KB per CU, x 64MB compulsory); only TLP doubles.
// Wave (kh, wn): rows 0..31 x cols wn*64..+64 over K-half kh (8 KSTEPs of 64).
// Two 32x64 A-tiles (one per K-half) staged in LDS per KSTEP, double-buffered;
// x prefetch depth-2 ping-pong; B depth-1 from L2-hot frag-major Wt2.
// Barrier = lgkmcnt(0)+s_barrier; vmcnt never drained in the loop.
#define KSTEP(KK, CUR, NXT, P0, P1)                                            \
    {                                                                          \
        const unsigned short* As_c = U16 + (CUR) * 4096 + kh * 2048;           \
        const int kb_ = (KK) >> 5;                                             \
        if ((KK) + 64 < 512) {                                                 \
            _Pragma("unroll")                                                  \
            for (int kf = 0; kf < 2; ++kf) {                                   \
                _Pragma("unroll")                                              \
                for (int f = 0; f < 4; ++f)                                    \
                    b[NXT][kf * 4 + f] = *(const bf16x8*)(gB + f * 16384 +     \
                                                     (kb_ + 2 + kf) * 512);    \
            }                                                                  \
            bf16x8 ha;                                                         \
            ha[0] = (__bf16)P0[0]; ha[1] = (__bf16)P0[1];                      \
            ha[2] = (__bf16)P0[2]; ha[3] = (__bf16)P0[3];                      \
            ha[4] = (__bf16)P1[0]; ha[5] = (__bf16)P1[1];                      \
            ha[6] = (__bf16)P1[2]; ha[7] = (__bf16)P1[3];                      \
            *(bf16x8*)&U16[(NXT) * 4096 + thT * 2048 + ldsA] = ha;             \
            if ((KK) + 192 < 512) {                                            \
                P0 = *(const floatx4*)(gA + (KK) + 192);                       \
                P1 = *(const floatx4*)(gA + (KK) + 196);                       \
            }                                                                  \
        }                                                                      \
        _Pragma("unroll")                                                      \
        for (int kf = 0; kf < 2; ++kf) {                                       \
            const int sw = kf ? sw1 : sw0;                                     \
            bf16x8 a0 = *(const bf16x8*)&As_c[lm * 64 + sw];                   \
            bf16x8 a1 = *(const bf16x8*)&As_c[(16 + lm) * 64 + sw];            \
            _Pragma("unroll")                                                  \
            for (int f = 0; f < 4; ++f) {                                      \
                acc[0][f] = __builtin_amdgcn_mfma_f32_16x16x32_bf16(           \
                    a0, b[CUR][kf * 4 + f], acc[0][f], 0, 0, 0);               \
                acc[1][f] = __builtin_amdgcn_mfma_f32_16x16x32_bf16(           \
                    a1, b[CUR][kf * 4 + f], acc[1][f], 0, 0, 0);               \
            }                                                                  \
        }                                                                      \
        asm volatile("s_waitcnt lgkmcnt(0)\n\ts_barrier" ::: "memory");        \
    }

__global__ __launch_bounds__(512, 4) void fused_main(
    const float* __restrict__ x, const float* __restrict__ bias,
    const unsigned short* __restrict__ Wt2, const unsigned short* __restrict__ Pbf,
    const float* __restrict__ pnorm2, float* __restrict__ out)
{
    // Union: A dbuf (2 buf x 2 half-tiles x 4KB = 16KB) | Rs reduce
    // (256 cols x RSTR f32 = 36.9KB) | Zs epilogue ([32][264] bf16 = 16.9KB).
    // Sequential uses, barrier-separated.
    __shared__ __align__(16) float Ubuf[DDIM * RSTR];   // 36864 B
    __shared__ float rn2[4][32];
    unsigned short* U16 = (unsigned short*)Ubuf;
    float* Rs = Ubuf;
    unsigned short* Zs = (unsigned short*)Ubuf;

    const int tid  = threadIdx.x;
    const int wave = tid >> 6;
    const int kh   = wave >> 2;          // K-half: 0 -> k<512, 1 -> k>=512
    const int wn   = wave & 3;           // col-group
    const int lane = tid & 63;
    const int lm   = lane & 15;
    const int lq   = lane >> 4;
    const int r0   = blockIdx.x * 32;

    // A staging: thread -> half-tile thT (tid>>8), row (tid&255)>>3, kb tid&7
    const int thT  = tid >> 8;
    const int rowA = (tid & 255) >> 3;
    const int kbA  = tid & 7;
    const float* gA = x + (size_t)(r0 + rowA) * KDIM + thT * 512 + kbA * 8;
    const int ldsA = rowA * 64 + ((kbA ^ (rowA & 7)) * 8);

    // B: frag-major Wt2; wave's cols at nblk=wn*4, K-half offset kh*16 kblks
    const unsigned short* gB = Wt2 + wn * 65536 + kh * 8192 + lane * 8;

    // A frag-read swizzle (rows lm and 16+lm share low-3 bits lm&7)
    const int sw0 = ((0 * 4 + lq) ^ (lm & 7)) * 8;
    const int sw1 = ((1 * 4 + lq) ^ (lm & 7)) * 8;

    floatx4 acc[2][4];
#pragma unroll
    for (int g = 0; g < 2; ++g)
#pragma unroll
        for (int f = 0; f < 4; ++f) { acc[g][f][0]=0.f; acc[g][f][1]=0.f; acc[g][f][2]=0.f; acc[g][f][3]=0.f; }

    bf16x8 b[2][8];   // [buf][kf*4+f] — statically indexed via KSTEP macro

    // ---- prologue: stage buf0 (kk=0); B kk=0; x prefetch kk=64 & 128 ----
    {
        floatx4 q0 = *(const floatx4*)(gA);
        floatx4 q1 = *(const floatx4*)(gA + 4);
        bf16x8 ha;
        ha[0] = (__bf16)q0[0]; ha[1] = (__bf16)q0[1];
        ha[2] = (__bf16)q0[2]; ha[3] = (__bf16)q0[3];
        ha[4] = (__bf16)q1[0]; ha[5] = (__bf16)q1[1];
        ha[6] = (__bf16)q1[2]; ha[7] = (__bf16)q1[3];
        *(bf16x8*)&U16[thT * 2048 + ldsA] = ha;
    }
#pragma unroll
    for (int kf = 0; kf < 2; ++kf)
#pragma unroll
        for (int f = 0; f < 4; ++f)
            b[0][kf * 4 + f] = *(const bf16x8*)(gB + f * 16384 + kf * 512);
    // depth-2 x prefetch: pa feeds even KSTEPs, pb odd
    floatx4 pa0 = *(const floatx4*)(gA + 64);
    floatx4 pa1 = *(const floatx4*)(gA + 68);
    floatx4 pb0 = *(const floatx4*)(gA + 128);
    floatx4 pb1 = *(const floatx4*)(gA + 132);
    asm volatile("s_waitcnt lgkmcnt(0)\n\ts_barrier" ::: "memory");

    for (int kk0 = 0; kk0 < 512; kk0 += 128) {
        KSTEP(kk0,      0, 1, pa0, pa1)
        KSTEP(kk0 + 64, 1, 0, pb0, pb1)
    }

    // ---- reduce K-halves: kh=1 writes partials, kh=0 accumulates ----
    if (kh == 1) {
#pragma unroll
        for (int g = 0; g < 2; ++g)
#pragma unroll
            for (int f = 0; f < 4; ++f)
                *(floatx4*)&Rs[(wn * 64 + f * 16 + lm) * RSTR + g * 16 + lq * 4] = acc[g][f];
    }
    __syncthreads();
    if (kh == 0) {
#pragma unroll
        for (int g = 0; g < 2; ++g)
#pragma unroll
            for (int f = 0; f < 4; ++f) {
                floatx4 p = *(const floatx4*)&Rs[(wn * 64 + f * 16 + lm) * RSTR + g * 16 + lq * 4];
#pragma unroll
                for (int r = 0; r < 4; ++r) acc[g][f][r] += p[r];
            }
        // ---- bias (once, on the merged sums) ----
#pragma unroll
        for (int f = 0; f < 4; ++f) {
            float bb = bias[wn * 64 + f * 16 + lm];
#pragma unroll
            for (int g = 0; g < 2; ++g)
#pragma unroll
                for (int r = 0; r < 4; ++r) acc[g][f][r] += bb;
        }
        // ---- partial row norms over this wave's 64 cols ----
#pragma unroll
        for (int g = 0; g < 2; ++g) {
            float s0 = 0.f, s1 = 0.f, s2 = 0.f, s3 = 0.f;
#pragma unroll
            for (int f = 0; f < 4; ++f) {
                s0 += acc[g][f][0] * acc[g][f][0];
                s1 += acc[g][f][1] * acc[g][f][1];
                s2 += acc[g][f][2] * acc[g][f][2];
                s3 += acc[g][f][3] * acc[g][f][3];
            }
#pragma unroll
            for (int m = 1; m < 16; m <<= 1) {
                s0 += __shfl_xor(s0, m, 64);
                s1 += __shfl_xor(s1, m, 64);
                s2 += __shfl_xor(s2, m, 64);
                s3 += __shfl_xor(s3, m, 64);
            }
            if (lm == 0) {
                int rl = g * 16 + lq * 4;
                rn2[wn][rl + 0] = s0;
                rn2[wn][rl + 1] = s1;
                rn2[wn][rl + 2] = s2;
                rn2[wn][rl + 3] = s3;
            }
        }
    }
    __syncthreads();   // all Rs reads done; Zs (same memory) now safe

    // ---- Z -> LDS bf16 for GEMM2 (kh=0 waves hold the merged Z) ----
    if (kh == 0) {
#pragma unroll
        for (int g = 0; g < 2; ++g)
#pragma unroll
            for (int f = 0; f < 4; ++f) {
                int col = wn * 64 + f * 16 + lm;
#pragma unroll
                for (int r = 0; r < 4; ++r)
                    Zs[(g * 16 + lq * 4 + r) * 264 + col] = f2b(acc[g][f][r]);
            }
    }
    __syncthreads();

    // ---- GEMM2: D2[class][row] = P @ Z^T, M=112 N=32 K=256; 1 ct/wave ----
    {
        const int ct = wave;
        if (ct < 7) {
            floatx4 acc2[2];
#pragma unroll
            for (int nf = 0; nf < 2; ++nf) { acc2[nf][0]=0.f; acc2[nf][1]=0.f; acc2[nf][2]=0.f; acc2[nf][3]=0.f; }
            const unsigned short* gP = Pbf + (ct * 16 + lm) * DDIM + lq * 8;
#pragma unroll
            for (int ks = 0; ks < 8; ++ks) {
                bf16x8 ap = *(const bf16x8*)(gP + ks * 32);   // L2-hot
#pragma unroll
                for (int nf = 0; nf < 2; ++nf) {
                    bf16x8 bz = *(const bf16x8*)&Zs[(nf * 16 + lm) * 264 + ks * 32 + lq * 8];
                    acc2[nf] = __builtin_amdgcn_mfma_f32_16x16x32_bf16(ap, bz, acc2[nf], 0, 0, 0);
                }
            }
            int c0 = ct * 16 + lq * 4;
            if (c0 < CNUM) {
                floatx4 pn = *(const floatx4*)(pnorm2 + c0);
#pragma unroll
                for (int nf = 0; nf < 2; ++nf) {
                    int rl = nf * 16 + lm;
                    float rn = rn2[0][rl] + rn2[1][rl] + rn2[2][rl] + rn2[3][rl];
                    floatx4 o;
#pragma unroll
                    for (int r = 0; r < 4; ++r)
                        o[r] = (2.f * acc2[nf][r] - rn - pn[r]) * (1.f / 256.f);
                    *(floatx4*)&out[(r0 + rl) * CNUM + c0] = o;
                }
            }
        }
    }
}

extern "C" void kernel_launch(void* const* d_in, const int* in_sizes, int n_in,
                              void* d_out, int out_size, void* d_ws, size_t ws_size,
                              hipStream_t stream) {
    const float* x = (const float*)d_in[0];
    const float* W = (const float*)d_in[1];
    const float* b = (const float*)d_in[2];
    const float* P = (const float*)d_in[3];
    float* out = (float*)d_out;

    unsigned short* Wt2 = (unsigned short*)d_ws;
    unsigned short* Pbf = Wt2 + KDIM * DDIM;
    float* pn2 = (float*)(Pbf + CPAD * DDIM);

    prep<<<256 + CPAD / 4, 256, 0, stream>>>(W, P, Wt2, Pbf, pn2);
    fused_main<<<BATCH / 32, 512, 0, stream>>>(x, b, Wt2, Pbf, pn2, out);
}

// Round 8
// 112.121 us; speedup vs baseline: 1.0205x; 1.0205x over previous
//
#include <hip/hip_runtime.h>

// Problem constants: B=16384, IN_DIM=1024, D=256, C=100
#define BATCH 16384
#define KDIM  1024
#define DDIM  256
#define CNUM  100
#define CPAD  112
#define RSTR  68   // Rs row stride (floats): 64 rows + pad, mult of 4 for b128

typedef __bf16 bf16x8 __attribute__((ext_vector_type(8)));
typedef float  floatx4 __attribute__((ext_vector_type(4)));

static __device__ __forceinline__ unsigned short f2b(float f) {
    return __builtin_bit_cast(unsigned short, (__bf16)f);
}

// ---------------- prep: W -> frag-major bf16 Wt2, P->bf16 + pnorm2 ----------
// Wt2 layout: element (n, k) with nblk=n>>4, lm=n&15, kblk=k>>5, lq=(k>>3)&3,
// j=k&7 lives at Wt2[(nblk*32 + kblk)*512 + (lq*16+lm)*8 + j].
__global__ __launch_bounds__(256) void prep(const float* __restrict__ W,
                                            const float* __restrict__ P,
                                            unsigned short* __restrict__ Wt2,
                                            unsigned short* __restrict__ Pbf,
                                            float* __restrict__ pnorm2) {
    __shared__ float T[32][33];
    const int bid = blockIdx.x;
    if (bid < 256) {
        const int k0 = (bid & 31) * 32;
        const int n0 = (bid >> 5) * 32;
        const int j  = threadIdx.x & 31;
        const int i0 = threadIdx.x >> 5;
#pragma unroll
        for (int l = 0; l < 4; ++l) {
            int i = i0 + l * 8;
            T[i][j] = W[(k0 + i) * DDIM + n0 + j];   // T[k-local][n-local]
        }
        __syncthreads();
        if (threadIdx.x < 128) {
            const int l  = threadIdx.x & 63;
            const int fn = threadIdx.x >> 6;
            const int lm = l & 15, lq = l >> 4;
            bf16x8 v;
#pragma unroll
            for (int jj = 0; jj < 8; ++jj)
                v[jj] = (__bf16)T[lq * 8 + jj][fn * 16 + lm];
            const int nblk = (n0 >> 4) + fn;
            const int kblk = k0 >> 5;
            *(bf16x8*)&Wt2[(nblk * 32 + kblk) * 512 + l * 8] = v;
        }
    } else {
        const int wave = threadIdx.x >> 6;
        const int lane = threadIdx.x & 63;
        const int c = (bid - 256) * 4 + wave;
        float s = 0.f;
#pragma unroll
        for (int jj = 0; jj < 4; ++jj) {
            int d = jj * 64 + lane;
            float v = (c < CNUM) ? P[c * DDIM + d] : 0.f;
            Pbf[c * DDIM + d] = f2b(v);
            s += v * v;
        }
#pragma unroll
        for (int m = 1; m < 64; m <<= 1) s += __shfl_xor(s, m, 64);
        if (lane == 0) pnorm2[c] = s;
    }
}

// ---------------- fused main -------------------------------------------------
// BM=64, SPLIT-K-2 x 8 col-groups: 1024 thr / 16 waves, grid 256 (1 block/CU)
// -> 4 waves/SIMD, with B traffic IDENTICAL to round 6 (each block reads Wt2
// once: 512KB, 134MB total). R7 proved TLP gains are cancelled if B traffic
// doubles; this moves TLP alone. VGPR diet for the <=128 gate (4 waves/SIMD):
// wave (kh, wn) owns rows 0..63 x cols wn*32..+32 over K-half kh ->
// acc[4][2]=32, B dbuf b[2][4]=32, x-prefetch 16, transients ~16 => ~120.
// __launch_bounds__(1024,4) enforces the cap. Two 64x64 A-half-tiles per KSTEP
// staged in LDS (1024 thr = 16B each), double-buffered; x depth-2 ping-pong;
// B depth-1 from L2-hot frag-major Wt2. Barrier = lgkmcnt(0)+s_barrier;
// vmcnt never drained in the loop. Epilogue: split-K reduce via Rs, then
// bias/norms/Zs/GEMM2.
#define KSTEP(KK, CUR, NXT, P0, P1)                                            \
    {                                                                          \
        const unsigned short* As_c = U16 + (CUR) * 8192 + kh * 4096;           \
        const int kb_ = (KK) >> 5;                                             \
        if ((KK) + 64 < 512) {                                                 \
            _Pragma("unroll")                                                  \
            for (int kf = 0; kf < 2; ++kf) {                                   \
                _Pragma("unroll")                                              \
                for (int f = 0; f < 2; ++f)                                    \
                    b[NXT][kf * 2 + f] = *(const bf16x8*)(gB + f * 16384 +     \
                                                     (kb_ + 2 + kf) * 512);    \
            }                                                                  \
            bf16x8 ha;                                                         \
            ha[0] = (__bf16)P0[0]; ha[1] = (__bf16)P0[1];                      \
            ha[2] = (__bf16)P0[2]; ha[3] = (__bf16)P0[3];                      \
            ha[4] = (__bf16)P1[0]; ha[5] = (__bf16)P1[1];                      \
            ha[6] = (__bf16)P1[2]; ha[7] = (__bf16)P1[3];                      \
            *(bf16x8*)&U16[(NXT) * 8192 + ldsA] = ha;                          \
            if ((KK) + 192 < 512) {                                            \
                P0 = *(const floatx4*)(gA + (KK) + 192);                       \
                P1 = *(const floatx4*)(gA + (KK) + 196);                       \
            }                                                                  \
        }                                                                      \
        _Pragma("unroll")                                                      \
        for (int kf = 0; kf < 2; ++kf) {                                       \
            const int sw = kf ? sw1 : sw0;                                     \
            bf16x8 a0 = *(const bf16x8*)&As_c[lm * 64 + sw];                   \
            bf16x8 a1 = *(const bf16x8*)&As_c[(16 + lm) * 64 + sw];            \
            bf16x8 a2 = *(const bf16x8*)&As_c[(32 + lm) * 64 + sw];            \
            bf16x8 a3 = *(const bf16x8*)&As_c[(48 + lm) * 64 + sw];            \
            _Pragma("unroll")                                                  \
            for (int f = 0; f < 2; ++f) {                                      \
                acc[0][f] = __builtin_amdgcn_mfma_f32_16x16x32_bf16(           \
                    a0, b[CUR][kf * 2 + f], acc[0][f], 0, 0, 0);               \
                acc[1][f] = __builtin_amdgcn_mfma_f32_16x16x32_bf16(           \
                    a1, b[CUR][kf * 2 + f], acc[1][f], 0, 0, 0);               \
                acc[2][f] = __builtin_amdgcn_mfma_f32_16x16x32_bf16(           \
                    a2, b[CUR][kf * 2 + f], acc[2][f], 0, 0, 0);               \
                acc[3][f] = __builtin_amdgcn_mfma_f32_16x16x32_bf16(           \
                    a3, b[CUR][kf * 2 + f], acc[3][f], 0, 0, 0);               \
            }                                                                  \
        }                                                                      \
        asm volatile("s_waitcnt lgkmcnt(0)\n\ts_barrier" ::: "memory");        \
    }

__global__ __launch_bounds__(1024, 4) void fused_main(
    const float* __restrict__ x, const float* __restrict__ bias,
    const unsigned short* __restrict__ Wt2, const unsigned short* __restrict__ Pbf,
    const float* __restrict__ pnorm2, float* __restrict__ out)
{
    // Union: A dbuf (2 buf x 2 halves x 8KB = 32KB) | Rs reduce (256 cols x
    // RSTR f32 = 69.6KB) | Zs epilogue ([64][264] bf16 = 33.8KB).
    __shared__ __align__(16) float Ubuf[DDIM * RSTR];   // 69632 B
    __shared__ float rn2[8][64];
    unsigned short* U16 = (unsigned short*)Ubuf;
    float* Rs = Ubuf;
    unsigned short* Zs = (unsigned short*)Ubuf;

    const int tid  = threadIdx.x;
    const int wave = tid >> 6;
    const int kh   = wave >> 3;          // K-half: 0 -> k<512, 1 -> k>=512
    const int wn   = wave & 7;           // col-group (32 cols each)
    const int lane = tid & 63;
    const int lm   = lane & 15;
    const int lq   = lane >> 4;
    const int r0   = blockIdx.x * 64;

    // A staging: 1024 thr stage 2 half-tiles (16KB): half tid>>9,
    // row (tid>>3)&63, k-block tid&7; one f32x8 load -> one bf16x8 ds_write.
    const int half = tid >> 9;
    const int rowA = (tid >> 3) & 63;
    const int kbA  = tid & 7;
    const float* gA = x + (size_t)(r0 + rowA) * KDIM + half * 512 + kbA * 8;
    const int ldsA = half * 4096 + rowA * 64 + ((kbA ^ (rowA & 7)) * 8);

    // B: frag-major Wt2; wave's 2 col-frags at nblk=wn*2(+f), K-half kh
    const unsigned short* gB = Wt2 + wn * 32768 + kh * 8192 + lane * 8;

    // A frag-read swizzle (rows g*16+lm -> low-3 bits lm&7)
    const int sw0 = ((0 * 4 + lq) ^ (lm & 7)) * 8;
    const int sw1 = ((1 * 4 + lq) ^ (lm & 7)) * 8;

    floatx4 acc[4][2];
#pragma unroll
    for (int g = 0; g < 4; ++g)
#pragma unroll
        for (int f = 0; f < 2; ++f) { acc[g][f][0]=0.f; acc[g][f][1]=0.f; acc[g][f][2]=0.f; acc[g][f][3]=0.f; }

    bf16x8 b[2][4];   // [buf][kf*2+f] — statically indexed via KSTEP macro

    // ---- prologue: stage buf0 (kk=0); B kk=0; x prefetch kk=64 & 128 ----
    {
        floatx4 q0 = *(const floatx4*)(gA);
        floatx4 q1 = *(const floatx4*)(gA + 4);
        bf16x8 ha;
        ha[0] = (__bf16)q0[0]; ha[1] = (__bf16)q0[1];
        ha[2] = (__bf16)q0[2]; ha[3] = (__bf16)q0[3];
        ha[4] = (__bf16)q1[0]; ha[5] = (__bf16)q1[1];
        ha[6] = (__bf16)q1[2]; ha[7] = (__bf16)q1[3];
        *(bf16x8*)&U16[ldsA] = ha;
    }
#pragma unroll
    for (int kf = 0; kf < 2; ++kf)
#pragma unroll
        for (int f = 0; f < 2; ++f)
            b[0][kf * 2 + f] = *(const bf16x8*)(gB + f * 16384 + kf * 512);
    // depth-2 x prefetch: pa feeds even KSTEPs, pb odd
    floatx4 pa0 = *(const floatx4*)(gA + 64);
    floatx4 pa1 = *(const floatx4*)(gA + 68);
    floatx4 pb0 = *(const floatx4*)(gA + 128);
    floatx4 pb1 = *(const floatx4*)(gA + 132);
    asm volatile("s_waitcnt lgkmcnt(0)\n\ts_barrier" ::: "memory");

    for (int kk0 = 0; kk0 < 512; kk0 += 128) {
        KSTEP(kk0,      0, 1, pa0, pa1)
        KSTEP(kk0 + 64, 1, 0, pb0, pb1)
    }

    // ---- reduce K-halves: kh=1 writes partials, kh=0 accumulates ----
    if (kh == 1) {
#pragma unroll
        for (int g = 0; g < 4; ++g)
#pragma unroll
            for (int f = 0; f < 2; ++f)
                *(floatx4*)&Rs[(wn * 32 + f * 16 + lm) * RSTR + g * 16 + lq * 4] = acc[g][f];
    }
    __syncthreads();
    if (kh == 0) {
#pragma unroll
        for (int g = 0; g < 4; ++g)
#pragma unroll
            for (int f = 0; f < 2; ++f) {
                floatx4 p = *(const floatx4*)&Rs[(wn * 32 + f * 16 + lm) * RSTR + g * 16 + lq * 4];
#pragma unroll
                for (int r = 0; r < 4; ++r) acc[g][f][r] += p[r];
            }
        // ---- bias (once, on the merged sums) ----
#pragma unroll
        for (int f = 0; f < 2; ++f) {
            float bb = bias[wn * 32 + f * 16 + lm];
#pragma unroll
            for (int g = 0; g < 4; ++g)
#pragma unroll
                for (int r = 0; r < 4; ++r) acc[g][f][r] += bb;
        }
        // ---- partial row norms over this wave's 32 cols ----
#pragma unroll
        for (int g = 0; g < 4; ++g) {
            float s0 = 0.f, s1 = 0.f, s2 = 0.f, s3 = 0.f;
#pragma unroll
            for (int f = 0; f < 2; ++f) {
                s0 += acc[g][f][0] * acc[g][f][0];
                s1 += acc[g][f][1] * acc[g][f][1];
                s2 += acc[g][f][2] * acc[g][f][2];
                s3 += acc[g][f][3] * acc[g][f][3];
            }
#pragma unroll
            for (int m = 1; m < 16; m <<= 1) {
                s0 += __shfl_xor(s0, m, 64);
                s1 += __shfl_xor(s1, m, 64);
                s2 += __shfl_xor(s2, m, 64);
                s3 += __shfl_xor(s3, m, 64);
            }
            if (lm == 0) {
                int rl = g * 16 + lq * 4;
                rn2[wn][rl + 0] = s0;
                rn2[wn][rl + 1] = s1;
                rn2[wn][rl + 2] = s2;
                rn2[wn][rl + 3] = s3;
            }
        }
    }
    __syncthreads();   // all Rs reads done; Zs (same memory) now safe

    // ---- Z -> LDS bf16 for GEMM2 (kh=0 waves hold the merged Z) ----
    if (kh == 0) {
#pragma unroll
        for (int g = 0; g < 4; ++g)
#pragma unroll
            for (int f = 0; f < 2; ++f) {
                int col = wn * 32 + f * 16 + lm;
#pragma unroll
                for (int r = 0; r < 4; ++r)
                    Zs[(g * 16 + lq * 4 + r) * 264 + col] = f2b(acc[g][f][r]);
            }
    }
    __syncthreads();

    // ---- GEMM2: D2[class][row] = P @ Z^T, M=112 N=64 K=256; 1 ct/wave ----
    {
        const int ct = wave;
        if (ct < 7) {
            floatx4 acc2[4];
#pragma unroll
            for (int nf = 0; nf < 4; ++nf) { acc2[nf][0]=0.f; acc2[nf][1]=0.f; acc2[nf][2]=0.f; acc2[nf][3]=0.f; }
            const unsigned short* gP = Pbf + (ct * 16 + lm) * DDIM + lq * 8;
#pragma unroll
            for (int ks = 0; ks < 8; ++ks) {
                bf16x8 ap = *(const bf16x8*)(gP + ks * 32);   // L2-hot
#pragma unroll
                for (int nf = 0; nf < 4; ++nf) {
                    bf16x8 bz = *(const bf16x8*)&Zs[(nf * 16 + lm) * 264 + ks * 32 + lq * 8];
                    acc2[nf] = __builtin_amdgcn_mfma_f32_16x16x32_bf16(ap, bz, acc2[nf], 0, 0, 0);
                }
            }
            int c0 = ct * 16 + lq * 4;
            if (c0 < CNUM) {
                floatx4 pn = *(const floatx4*)(pnorm2 + c0);
#pragma unroll
                for (int nf = 0; nf < 4; ++nf) {
                    int rl = nf * 16 + lm;
                    float rn = rn2[0][rl] + rn2[1][rl] + rn2[2][rl] + rn2[3][rl]
                             + rn2[4][rl] + rn2[5][rl] + rn2[6][rl] + rn2[7][rl];
                    floatx4 o;
#pragma unroll
                    for (int r = 0; r < 4; ++r)
                        o[r] = (2.f * acc2[nf][r] - rn - pn[r]) * (1.f / 256.f);
                    *(floatx4*)&out[(r0 + rl) * CNUM + c0] = o;
                }
            }
        }
    }
}

extern "C" void kernel_launch(void* const* d_in, const int* in_sizes, int n_in,
                              void* d_out, int out_size, void* d_ws, size_t ws_size,
                              hipStream_t stream) {
    const float* x = (const float*)d_in[0];
    const float* W = (const float*)d_in[1];
    const float* b = (const float*)d_in[2];
    const float* P = (const float*)d_in[3];
    float* out = (float*)d_out;

    unsigned short* Wt2 = (unsigned short*)d_ws;
    unsigned short* Pbf = Wt2 + KDIM * DDIM;
    float* pn2 = (float*)(Pbf + CPAD * DDIM);

    prep<<<256 + CPAD / 4, 256, 0, stream>>>(W, P, Wt2, Pbf, pn2);
    fused_main<<<BATCH / 64, 1024, 0, stream>>>(x, b, Wt2, Pbf, pn2, out);
}

// Round 9
// 110.895 us; speedup vs baseline: 1.0318x; 1.0111x over previous
//
#include <hip/hip_runtime.h>

// Problem constants: B=16384, IN_DIM=1024, D=256, C=100
#define BATCH 16384
#define KDIM  1024
#define DDIM  256
#define CNUM  100
#define CPAD  112
#define RSTR  72   // Rs row stride (floats): mult of 4 for b128

typedef __bf16 bf16x8 __attribute__((ext_vector_type(8)));
typedef float  floatx4 __attribute__((ext_vector_type(4)));

static __device__ __forceinline__ unsigned short f2b(float f) {
    return __builtin_bit_cast(unsigned short, (__bf16)f);
}

// ---------------- prep: W -> frag-major bf16 Wt2, P->bf16 + pnorm2 ----------
// Wt2 layout: element (n, k) with nblk=n>>4, lm=n&15, kblk=k>>5, lq=(k>>3)&3,
// j=k&7 lives at Wt2[(nblk*32 + kblk)*512 + (lq*16+lm)*8 + j].
__global__ __launch_bounds__(256) void prep(const float* __restrict__ W,
                                            const float* __restrict__ P,
                                            unsigned short* __restrict__ Wt2,
                                            unsigned short* __restrict__ Pbf,
                                            float* __restrict__ pnorm2) {
    __shared__ float T[32][33];
    const int bid = blockIdx.x;
    if (bid < 256) {
        const int k0 = (bid & 31) * 32;
        const int n0 = (bid >> 5) * 32;
        const int j  = threadIdx.x & 31;
        const int i0 = threadIdx.x >> 5;
#pragma unroll
        for (int l = 0; l < 4; ++l) {
            int i = i0 + l * 8;
            T[i][j] = W[(k0 + i) * DDIM + n0 + j];   // T[k-local][n-local]
        }
        __syncthreads();
        if (threadIdx.x < 128) {
            const int l  = threadIdx.x & 63;
            const int fn = threadIdx.x >> 6;
            const int lm = l & 15, lq = l >> 4;
            bf16x8 v;
#pragma unroll
            for (int jj = 0; jj < 8; ++jj)
                v[jj] = (__bf16)T[lq * 8 + jj][fn * 16 + lm];
            const int nblk = (n0 >> 4) + fn;
            const int kblk = k0 >> 5;
            *(bf16x8*)&Wt2[(nblk * 32 + kblk) * 512 + l * 8] = v;
        }
    } else {
        const int wave = threadIdx.x >> 6;
        const int lane = threadIdx.x & 63;
        const int c = (bid - 256) * 4 + wave;
        float s = 0.f;
#pragma unroll
        for (int jj = 0; jj < 4; ++jj) {
            int d = jj * 64 + lane;
            float v = (c < CNUM) ? P[c * DDIM + d] : 0.f;
            Pbf[c * DDIM + d] = f2b(v);
            s += v * v;
        }
#pragma unroll
        for (int m = 1; m < 64; m <<= 1) s += __shfl_xor(s, m, 64);
        if (lane == 0) pnorm2[c] = s;
    }
}

// ---------------- fused main -------------------------------------------------
// R6 geometry (best: 112.05us) with HALVED SYNC EVENTS: BM=64, split-K-2,
// 512 thr / 8 waves, grid 256 (1 block/CU, 2 waves/SIMD). Wave (kh, wn):
// rows 0..63 x cols wn*64..+64 over K-half kh. NEW: one barrier per 128-k
// PAIR (4 barriers/loop instead of 8), 64 MFMA/wave between barriers.
// A: 2 buffers x (2 halves x 64x128 bf16 = 32KB) in LDS; staging = 4 f32x4-
// pair loads + 4 bf16x8 ds_writes per thread per pair, loads issued one full
// pair-phase ahead (p[8] regs). B never touches LDS: rolling granule (64-k)
// ping-pong b[2][8], prefetch issued right after the granule that frees the
// buffer (~1.5 granule slack). Barrier = lgkmcnt(0)+s_barrier; vmcnt never
// drained in the loop. Epilogue: split-K reduce via Rs, bias/norms/Zs/GEMM2.
#define CVT8(H, A_, B_)                                                        \
    H[0] = (__bf16)A_[0]; H[1] = (__bf16)A_[1];                                \
    H[2] = (__bf16)A_[2]; H[3] = (__bf16)A_[3];                                \
    H[4] = (__bf16)B_[0]; H[5] = (__bf16)B_[1];                                \
    H[6] = (__bf16)B_[2]; H[7] = (__bf16)B_[3];

#define MFMA_(A_, B_, C_) __builtin_amdgcn_mfma_f32_16x16x32_bf16(A_, B_, C_, 0, 0, 0)

// One 64-k granule: 8 ds_read_b128 + 32 MFMA; then prefetch B for granule G+2
// into the buffer just consumed (b[G&1]) — register dep keeps order.
#define GRAN(G, CUR)                                                           \
    {                                                                          \
        const unsigned short* As_c = U16 + (CUR) * 16384 + kh * 8192;          \
        _Pragma("unroll")                                                      \
        for (int kf = 0; kf < 2; ++kf) {                                       \
            const int sw = ((((G) & 1) * 8 + kf * 4 + lq) ^ lm) * 8;           \
            bf16x8 a0 = *(const bf16x8*)&As_c[lm * 128 + sw];                  \
            bf16x8 a1 = *(const bf16x8*)&As_c[(16 + lm) * 128 + sw];           \
            bf16x8 a2 = *(const bf16x8*)&As_c[(32 + lm) * 128 + sw];           \
            bf16x8 a3 = *(const bf16x8*)&As_c[(48 + lm) * 128 + sw];           \
            _Pragma("unroll")                                                  \
            for (int f = 0; f < 4; ++f) {                                      \
                acc[0][f] = MFMA_(a0, b[(G) & 1][kf * 4 + f], acc[0][f]);      \
                acc[1][f] = MFMA_(a1, b[(G) & 1][kf * 4 + f], acc[1][f]);      \
                acc[2][f] = MFMA_(a2, b[(G) & 1][kf * 4 + f], acc[2][f]);      \
                acc[3][f] = MFMA_(a3, b[(G) & 1][kf * 4 + f], acc[3][f]);      \
            }                                                                  \
        }                                                                      \
        if ((G) + 2 < 8) {                                                     \
            _Pragma("unroll")                                                  \
            for (int kf = 0; kf < 2; ++kf)                                     \
                _Pragma("unroll")                                              \
                for (int f = 0; f < 4; ++f)                                    \
                    b[(G) & 1][kf * 4 + f] = *(const bf16x8*)(gB +             \
                        f * 16384 + (((G) + 2) * 2 + kf) * 512);               \
        }                                                                      \
    }

// One 128-k pair: stage pair T+1 (from p regs), issue loads for pair T+2,
// two granules of MFMA, one barrier.
#define PAIRSTEP(T, CUR, NXT)                                                  \
    {                                                                          \
        if ((T) < 3) {                                                         \
            bf16x8 h0, h1, h2, h3;                                             \
            CVT8(h0, p[0], p[1]) CVT8(h1, p[2], p[3])                          \
            CVT8(h2, p[4], p[5]) CVT8(h3, p[6], p[7])                          \
            *(bf16x8*)&U16[(NXT) * 16384 + ldsW0] = h0;                        \
            *(bf16x8*)&U16[(NXT) * 16384 + ldsW1] = h1;                        \
            *(bf16x8*)&U16[(NXT) * 16384 + 8192 + ldsW0] = h2;                 \
            *(bf16x8*)&U16[(NXT) * 16384 + 8192 + ldsW1] = h3;                 \
            if ((T) < 2) {                                                     \
                p[0] = *(const floatx4*)(gA + ((T) + 2) * 128);                \
                p[1] = *(const floatx4*)(gA + ((T) + 2) * 128 + 4);            \
                p[2] = *(const floatx4*)(gA + ((T) + 2) * 128 + 64);           \
                p[3] = *(const floatx4*)(gA + ((T) + 2) * 128 + 68);           \
                p[4] = *(const floatx4*)(gA + 512 + ((T) + 2) * 128);          \
                p[5] = *(const floatx4*)(gA + 512 + ((T) + 2) * 128 + 4);      \
                p[6] = *(const floatx4*)(gA + 512 + ((T) + 2) * 128 + 64);     \
                p[7] = *(const floatx4*)(gA + 512 + ((T) + 2) * 128 + 68);     \
            }                                                                  \
        }                                                                      \
        GRAN(2 * (T), CUR)                                                     \
        GRAN(2 * (T) + 1, CUR)                                                 \
        asm volatile("s_waitcnt lgkmcnt(0)\n\ts_barrier" ::: "memory");        \
    }

__global__ __launch_bounds__(512, 2) void fused_main(
    const float* __restrict__ x, const float* __restrict__ bias,
    const unsigned short* __restrict__ Wt2, const unsigned short* __restrict__ Pbf,
    const float* __restrict__ pnorm2, float* __restrict__ out)
{
    // Union: A dbuf (2 x 32KB = 64KB) | Rs reduce (256 x RSTR f32 = 73.7KB) |
    // Zs epilogue ([64][264] bf16 = 33.8KB). Sequential, barrier-separated.
    __shared__ __align__(16) float Ubuf[DDIM * RSTR];   // 73728 B
    __shared__ float rn2[4][64];
    unsigned short* U16 = (unsigned short*)Ubuf;
    float* Rs = Ubuf;
    unsigned short* Zs = (unsigned short*)Ubuf;

    const int tid  = threadIdx.x;
    const int wave = tid >> 6;
    const int kh   = wave >> 2;          // K-half: 0 -> k<512, 1 -> k>=512
    const int wn   = wave & 3;           // col-group (64 cols each)
    const int lane = tid & 63;
    const int lm   = lane & 15;
    const int lq   = lane >> 4;
    const int r0   = blockIdx.x * 64;

    // A staging: thread -> row tid>>3 (0..63), k-block kbA = tid&7; per pair
    // it stages k-slots kbA and kbA+8 for BOTH K-halves (4 loads, 4 writes).
    const int rowA = tid >> 3;
    const int kbA  = tid & 7;
    const float* gA = x + (size_t)(r0 + rowA) * KDIM + kbA * 8;
    // 16-slot XOR swizzle (slots of 8 shorts within a 128-k row)
    const int ldsW0 = rowA * 128 + ((kbA ^ (rowA & 15)) * 8);
    const int ldsW1 = rowA * 128 + (((kbA + 8) ^ (rowA & 15)) * 8);

    // B: frag-major Wt2; wave's cols at nblk=wn*4, K-half offset kh*16 kblks
    const unsigned short* gB = Wt2 + wn * 65536 + kh * 8192 + lane * 8;

    floatx4 acc[4][4];
#pragma unroll
    for (int g = 0; g < 4; ++g)
#pragma unroll
        for (int f = 0; f < 4; ++f) { acc[g][f][0]=0.f; acc[g][f][1]=0.f; acc[g][f][2]=0.f; acc[g][f][3]=0.f; }

    bf16x8  b[2][8];   // rolling granule ping-pong (statically indexed)
    floatx4 p[8];      // x pair-prefetch (statically indexed)

    // ---- prologue: stage pair 0 into buf0; B granules 0,1; load pair-1 x ---
    {
        floatx4 q0 = *(const floatx4*)(gA);
        floatx4 q1 = *(const floatx4*)(gA + 4);
        floatx4 q2 = *(const floatx4*)(gA + 64);
        floatx4 q3 = *(const floatx4*)(gA + 68);
        floatx4 q4 = *(const floatx4*)(gA + 512);
        floatx4 q5 = *(const floatx4*)(gA + 516);
        floatx4 q6 = *(const floatx4*)(gA + 576);
        floatx4 q7 = *(const floatx4*)(gA + 580);
        bf16x8 h0, h1, h2, h3;
        CVT8(h0, q0, q1) CVT8(h1, q2, q3) CVT8(h2, q4, q5) CVT8(h3, q6, q7)
        *(bf16x8*)&U16[ldsW0] = h0;
        *(bf16x8*)&U16[ldsW1] = h1;
        *(bf16x8*)&U16[8192 + ldsW0] = h2;
        *(bf16x8*)&U16[8192 + ldsW1] = h3;
    }
#pragma unroll
    for (int kf = 0; kf < 2; ++kf)
#pragma unroll
        for (int f = 0; f < 4; ++f) {
            b[0][kf * 4 + f] = *(const bf16x8*)(gB + f * 16384 + kf * 512);
            b[1][kf * 4 + f] = *(const bf16x8*)(gB + f * 16384 + (2 + kf) * 512);
        }
    p[0] = *(const floatx4*)(gA + 128);
    p[1] = *(const floatx4*)(gA + 132);
    p[2] = *(const floatx4*)(gA + 192);
    p[3] = *(const floatx4*)(gA + 196);
    p[4] = *(const floatx4*)(gA + 640);
    p[5] = *(const floatx4*)(gA + 644);
    p[6] = *(const floatx4*)(gA + 704);
    p[7] = *(const floatx4*)(gA + 708);
    asm volatile("s_waitcnt lgkmcnt(0)\n\ts_barrier" ::: "memory");

    // ---- K loop: 4 pair-steps, one barrier each ----
    PAIRSTEP(0, 0, 1)
    PAIRSTEP(1, 1, 0)
    PAIRSTEP(2, 0, 1)
    PAIRSTEP(3, 1, 0)

    // ---- reduce K-halves: kh=1 writes partials, kh=0 accumulates ----
    if (kh == 1) {
#pragma unroll
        for (int g = 0; g < 4; ++g)
#pragma unroll
            for (int f = 0; f < 4; ++f)
                *(floatx4*)&Rs[(wn * 64 + f * 16 + lm) * RSTR + g * 16 + lq * 4] = acc[g][f];
    }
    __syncthreads();
    if (kh == 0) {
#pragma unroll
        for (int g = 0; g < 4; ++g)
#pragma unroll
            for (int f = 0; f < 4; ++f) {
                floatx4 pp = *(const floatx4*)&Rs[(wn * 64 + f * 16 + lm) * RSTR + g * 16 + lq * 4];
#pragma unroll
                for (int r = 0; r < 4; ++r) acc[g][f][r] += pp[r];
            }
        // ---- bias (once, on the merged sums) ----
#pragma unroll
        for (int f = 0; f < 4; ++f) {
            float bb = bias[wn * 64 + f * 16 + lm];
#pragma unroll
            for (int g = 0; g < 4; ++g)
#pragma unroll
                for (int r = 0; r < 4; ++r) acc[g][f][r] += bb;
        }
        // ---- partial row norms over this wave's 64 cols ----
#pragma unroll
        for (int g = 0; g < 4; ++g) {
            float s0 = 0.f, s1 = 0.f, s2 = 0.f, s3 = 0.f;
#pragma unroll
            for (int f = 0; f < 4; ++f) {
                s0 += acc[g][f][0] * acc[g][f][0];
                s1 += acc[g][f][1] * acc[g][f][1];
                s2 += acc[g][f][2] * acc[g][f][2];
                s3 += acc[g][f][3] * acc[g][f][3];
            }
#pragma unroll
            for (int m = 1; m < 16; m <<= 1) {
                s0 += __shfl_xor(s0, m, 64);
                s1 += __shfl_xor(s1, m, 64);
                s2 += __shfl_xor(s2, m, 64);
                s3 += __shfl_xor(s3, m, 64);
            }
            if (lm == 0) {
                int rl = g * 16 + lq * 4;
                rn2[wn][rl + 0] = s0;
                rn2[wn][rl + 1] = s1;
                rn2[wn][rl + 2] = s2;
                rn2[wn][rl + 3] = s3;
            }
        }
    }
    __syncthreads();   // all Rs reads done; Zs (same memory) now safe

    // ---- Z -> LDS bf16 for GEMM2 (kh=0 waves hold the merged Z) ----
    if (kh == 0) {
#pragma unroll
        for (int g = 0; g < 4; ++g)
#pragma unroll
            for (int f = 0; f < 4; ++f) {
                int col = wn * 64 + f * 16 + lm;
#pragma unroll
                for (int r = 0; r < 4; ++r)
                    Zs[(g * 16 + lq * 4 + r) * 264 + col] = f2b(acc[g][f][r]);
            }
    }
    __syncthreads();

    // ---- GEMM2: D2[class][row] = P @ Z^T, M=112 N=64 K=256; 1 ct/wave ----
    {
        const int ct = wave;
        if (ct < 7) {
            floatx4 acc2[4];
#pragma unroll
            for (int nf = 0; nf < 4; ++nf) { acc2[nf][0]=0.f; acc2[nf][1]=0.f; acc2[nf][2]=0.f; acc2[nf][3]=0.f; }
            const unsigned short* gP = Pbf + (ct * 16 + lm) * DDIM + lq * 8;
#pragma unroll
            for (int ks = 0; ks < 8; ++ks) {
                bf16x8 ap = *(const bf16x8*)(gP + ks * 32);   // L2-hot
#pragma unroll
                for (int nf = 0; nf < 4; ++nf) {
                    bf16x8 bz = *(const bf16x8*)&Zs[(nf * 16 + lm) * 264 + ks * 32 + lq * 8];
                    acc2[nf] = __builtin_amdgcn_mfma_f32_16x16x32_bf16(ap, bz, acc2[nf], 0, 0, 0);
                }
            }
            int c0 = ct * 16 + lq * 4;
            if (c0 < CNUM) {
                floatx4 pn = *(const floatx4*)(pnorm2 + c0);
#pragma unroll
                for (int nf = 0; nf < 4; ++nf) {
                    int rl = nf * 16 + lm;
                    float rn = rn2[0][rl] + rn2[1][rl] + rn2[2][rl] + rn2[3][rl];
                    floatx4 o;
#pragma unroll
                    for (int r = 0; r < 4; ++r)
                        o[r] = (2.f * acc2[nf][r] - rn - pn[r]) * (1.f / 256.f);
                    *(floatx4*)&out[(r0 + rl) * CNUM + c0] = o;
                }
            }
        }
    }
}

extern "C" void kernel_launch(void* const* d_in, const int* in_sizes, int n_in,
                              void* d_out, int out_size, void* d_ws, size_t ws_size,
                              hipStream_t stream) {
    const float* x = (const float*)d_in[0];
    const float* W = (const float*)d_in[1];
    const float* b = (const float*)d_in[2];
    const float* P = (const float*)d_in[3];
    float* out = (float*)d_out;

    unsigned short* Wt2 = (unsigned short*)d_ws;
    unsigned short* Pbf = Wt2 + KDIM * DDIM;
    float* pn2 = (float*)(Pbf + CPAD * DDIM);

    prep<<<256 + CPAD / 4, 256, 0, stream>>>(W, P, Wt2, Pbf, pn2);
    fused_main<<<BATCH / 64, 512, 0, stream>>>(x, b, Wt2, Pbf, pn2, out);
}

// Round 10
// 110.756 us; speedup vs baseline: 1.0331x; 1.0013x over previous
//
#include <hip/hip_runtime.h>

// Problem constants: B=16384, IN_DIM=1024, D=256, C=100
#define BATCH 16384
#define KDIM  1024
#define DDIM  256
#define CNUM  100
#define CPAD  112
#define RSTR  72   // Rs row stride (floats): mult of 4 for b128

typedef __bf16 bf16x8 __attribute__((ext_vector_type(8)));
typedef float  floatx4 __attribute__((ext_vector_type(4)));

static __device__ __forceinline__ unsigned short f2b(float f) {
    return __builtin_bit_cast(unsigned short, (__bf16)f);
}

// ---------------- prep: W -> frag-major bf16 Wt2, P->bf16 + pnorm2 ----------
// Wt2 layout: element (n, k) with nblk=n>>4, lm=n&15, kblk=k>>5, lq=(k>>3)&3,
// j=k&7 lives at Wt2[(nblk*32 + kblk)*512 + (lq*16+lm)*8 + j].
__global__ __launch_bounds__(256) void prep(const float* __restrict__ W,
                                            const float* __restrict__ P,
                                            unsigned short* __restrict__ Wt2,
                                            unsigned short* __restrict__ Pbf,
                                            float* __restrict__ pnorm2) {
    __shared__ float T[32][33];
    const int bid = blockIdx.x;
    if (bid < 256) {
        const int k0 = (bid & 31) * 32;
        const int n0 = (bid >> 5) * 32;
        const int j  = threadIdx.x & 31;
        const int i0 = threadIdx.x >> 5;
#pragma unroll
        for (int l = 0; l < 4; ++l) {
            int i = i0 + l * 8;
            T[i][j] = W[(k0 + i) * DDIM + n0 + j];   // T[k-local][n-local]
        }
        __syncthreads();
        if (threadIdx.x < 128) {
            const int l  = threadIdx.x & 63;
            const int fn = threadIdx.x >> 6;
            const int lm = l & 15, lq = l >> 4;
            bf16x8 v;
#pragma unroll
            for (int jj = 0; jj < 8; ++jj)
                v[jj] = (__bf16)T[lq * 8 + jj][fn * 16 + lm];
            const int nblk = (n0 >> 4) + fn;
            const int kblk = k0 >> 5;
            *(bf16x8*)&Wt2[(nblk * 32 + kblk) * 512 + l * 8] = v;
        }
    } else {
        const int wave = threadIdx.x >> 6;
        const int lane = threadIdx.x & 63;
        const int c = (bid - 256) * 4 + wave;
        float s = 0.f;
#pragma unroll
        for (int jj = 0; jj < 4; ++jj) {
            int d = jj * 64 + lane;
            float v = (c < CNUM) ? P[c * DDIM + d] : 0.f;
            Pbf[c * DDIM + d] = f2b(v);
            s += v * v;
        }
#pragma unroll
        for (int m = 1; m < 64; m <<= 1) s += __shfl_xor(s, m, 64);
        if (lane == 0) pnorm2[c] = s;
    }
}

// ---------------- fused main -------------------------------------------------
// R9 geometry (best: 110.9us) with barriers 4 -> 2: QUAD-STEP of 256 k per
// barrier. BM=64, split-K-2, 512 thr / 8 waves, grid 256 (1 block/CU,
// 2 waves/SIMD). Wave (kh, wn): rows 0..63 x cols wn*64..+64 over K-half kh.
// A dbuf: 2 x (2 halves x 64 rows x 256 k bf16) = 128KB LDS; 128 MFMA/wave
// between barriers. Staging per quad = 2 tranches of 8 floatx4 regs (pA/pB
// ping-pong, static indexing); tranche loads issued ~2 granules before their
// ds_writes. B never in LDS: rolling 64-k granule ping-pong b[2][8], prefetch
// distance 2 (L2-hot). Barrier = lgkmcnt(0)+s_barrier; vmcnt never drained.
// Epilogue: split-K reduce via Rs, bias/norms/Zs/GEMM2.
#define CVT8(H, A_, B_)                                                        \
    H[0] = (__bf16)A_[0]; H[1] = (__bf16)A_[1];                                \
    H[2] = (__bf16)A_[2]; H[3] = (__bf16)A_[3];                                \
    H[4] = (__bf16)B_[0]; H[5] = (__bf16)B_[1];                                \
    H[6] = (__bf16)B_[2]; H[7] = (__bf16)B_[3];

#define MFMA_(A_, B_, C_) __builtin_amdgcn_mfma_f32_16x16x32_bf16(A_, B_, C_, 0, 0, 0)

// issue the 8 x-loads of tranche T (T=0,1) of quad Q into reg set PP
#define STAGE_LD(PP, Q, T)                                                     \
    PP[0] = *(const floatx4*)(gA + (Q) * 256 + (T) * 128);                     \
    PP[1] = *(const floatx4*)(gA + (Q) * 256 + (T) * 128 + 4);                 \
    PP[2] = *(const floatx4*)(gA + (Q) * 256 + (T) * 128 + 64);                \
    PP[3] = *(const floatx4*)(gA + (Q) * 256 + (T) * 128 + 68);                \
    PP[4] = *(const floatx4*)(gA + 512 + (Q) * 256 + (T) * 128);               \
    PP[5] = *(const floatx4*)(gA + 512 + (Q) * 256 + (T) * 128 + 4);           \
    PP[6] = *(const floatx4*)(gA + 512 + (Q) * 256 + (T) * 128 + 64);          \
    PP[7] = *(const floatx4*)(gA + 512 + (Q) * 256 + (T) * 128 + 68);

// convert reg set PP -> bf16 and write tranche T into buffer BUF
#define STAGE_WR(PP, BUF, T)                                                   \
    {                                                                          \
        bf16x8 h0, h1, h2, h3;                                                 \
        CVT8(h0, PP[0], PP[1]) CVT8(h1, PP[2], PP[3])                          \
        CVT8(h2, PP[4], PP[5]) CVT8(h3, PP[6], PP[7])                          \
        *(bf16x8*)&U16[(BUF) * 32768 + w0 + (T) * 128] = h0;                   \
        *(bf16x8*)&U16[(BUF) * 32768 + w1 + (T) * 128] = h1;                   \
        *(bf16x8*)&U16[(BUF) * 32768 + 16384 + w0 + (T) * 128] = h2;           \
        *(bf16x8*)&U16[(BUF) * 32768 + 16384 + w1 + (T) * 128] = h3;           \
    }

// One 64-k granule: 8 ds_read_b128 + 32 MFMA; prefetch B granule G+2 into the
// buffer just consumed.
#define GRAN(G, CUR)                                                           \
    {                                                                          \
        const unsigned short* As_c = U16 + (CUR) * 32768 + kh * 16384;         \
        _Pragma("unroll")                                                      \
        for (int kf = 0; kf < 2; ++kf) {                                       \
            const int sw = ((((G) & 3) * 8 + kf * 4 + lq) ^ lm) * 8;           \
            bf16x8 a0 = *(const bf16x8*)&As_c[lm * 256 + sw];                  \
            bf16x8 a1 = *(const bf16x8*)&As_c[(16 + lm) * 256 + sw];           \
            bf16x8 a2 = *(const bf16x8*)&As_c[(32 + lm) * 256 + sw];           \
            bf16x8 a3 = *(const bf16x8*)&As_c[(48 + lm) * 256 + sw];           \
            _Pragma("unroll")                                                  \
            for (int f = 0; f < 4; ++f) {                                      \
                acc[0][f] = MFMA_(a0, b[(G) & 1][kf * 4 + f], acc[0][f]);      \
                acc[1][f] = MFMA_(a1, b[(G) & 1][kf * 4 + f], acc[1][f]);      \
                acc[2][f] = MFMA_(a2, b[(G) & 1][kf * 4 + f], acc[2][f]);      \
                acc[3][f] = MFMA_(a3, b[(G) & 1][kf * 4 + f], acc[3][f]);      \
            }                                                                  \
        }                                                                      \
        if ((G) + 2 < 8) {                                                     \
            _Pragma("unroll")                                                  \
            for (int kf = 0; kf < 2; ++kf)                                     \
                _Pragma("unroll")                                              \
                for (int f = 0; f < 4; ++f)                                    \
                    b[(G) & 1][kf * 4 + f] = *(const bf16x8*)(gB +             \
                        f * 16384 + (((G) + 2) * 2 + kf) * 512);               \
        }                                                                      \
    }

#define BARRIER asm volatile("s_waitcnt lgkmcnt(0)\n\ts_barrier" ::: "memory");

__global__ __launch_bounds__(512, 2) void fused_main(
    const float* __restrict__ x, const float* __restrict__ bias,
    const unsigned short* __restrict__ Wt2, const unsigned short* __restrict__ Pbf,
    const float* __restrict__ pnorm2, float* __restrict__ out)
{
    // Union: A dbuf (2 x 64KB = 128KB) | Rs reduce (256 x RSTR f32 = 73.7KB) |
    // Zs epilogue ([64][264] bf16 = 33.8KB). Sequential, barrier-separated.
    __shared__ __align__(16) float Ubuf[32768];   // 131072 B
    __shared__ float rn2[4][64];
    unsigned short* U16 = (unsigned short*)Ubuf;
    float* Rs = Ubuf;
    unsigned short* Zs = (unsigned short*)Ubuf;

    const int tid  = threadIdx.x;
    const int wave = tid >> 6;
    const int kh   = wave >> 2;          // K-half: 0 -> k<512, 1 -> k>=512
    const int wn   = wave & 3;           // col-group (64 cols each)
    const int lane = tid & 63;
    const int lm   = lane & 15;
    const int lq   = lane >> 4;
    const int r0   = blockIdx.x * 64;

    // A staging: thread -> row tid>>3 (0..63), k-slot base kbA = tid&7; per
    // quad it stages slots {kbA, kbA+8, kbA+16, kbA+24} for BOTH K-halves.
    const int rowA = tid >> 3;
    const int kbA  = tid & 7;
    const float* gA = x + (size_t)(r0 + rowA) * KDIM + kbA * 8;
    const int m15 = rowA & 15;
    const int w0 = rowA * 256 + ((kbA ^ m15) * 8);          // slot kbA
    const int w1 = rowA * 256 + (((kbA + 8) ^ m15) * 8);    // slot kbA+8
    // (slots +16/+24 are w0/w1 + 128 shorts: bit4 untouched by 4-bit XOR)

    // B: frag-major Wt2; wave's cols at nblk=wn*4, K-half offset kh*16 kblks
    const unsigned short* gB = Wt2 + wn * 65536 + kh * 8192 + lane * 8;

    floatx4 acc[4][4];
#pragma unroll
    for (int g = 0; g < 4; ++g)
#pragma unroll
        for (int f = 0; f < 4; ++f) { acc[g][f][0]=0.f; acc[g][f][1]=0.f; acc[g][f][2]=0.f; acc[g][f][3]=0.f; }

    bf16x8  b[2][8];      // rolling granule ping-pong (static indexing)
    floatx4 pA[8], pB[8]; // x tranche prefetch sets (static indexing)

    // ---- prologue ----
    STAGE_LD(pA, 0, 0)                 // quad0 tranche0
    STAGE_LD(pB, 0, 1)                 // quad0 tranche1
#pragma unroll
    for (int kf = 0; kf < 2; ++kf)
#pragma unroll
        for (int f = 0; f < 4; ++f) {
            b[0][kf * 4 + f] = *(const bf16x8*)(gB + f * 16384 + kf * 512);
            b[1][kf * 4 + f] = *(const bf16x8*)(gB + f * 16384 + (2 + kf) * 512);
        }
    STAGE_WR(pA, 0, 0)                 // buf0 tranche0 (waits pA)
    STAGE_LD(pA, 1, 0)                 // quad1 tranche0 (early issue)
    STAGE_WR(pB, 0, 1)                 // buf0 tranche1
    BARRIER                            // buf0 ready

    // ---- quad-step 0: compute buf0 granules 0-3, stage buf1 ----
    STAGE_WR(pA, 1, 0)                 // buf1 tranche0
    STAGE_LD(pB, 1, 1)                 // quad1 tranche1 (issue before MFMAs)
    GRAN(0, 0)
    GRAN(1, 0)
    STAGE_WR(pB, 1, 1)                 // buf1 tranche1 (covered by 64 MFMA)
    GRAN(2, 0)
    GRAN(3, 0)
    BARRIER                            // buf1 ready, buf0 dead

    // ---- quad-step 1: compute buf1 granules 4-7 ----
    GRAN(4, 1)
    GRAN(5, 1)
    GRAN(6, 1)
    GRAN(7, 1)
    BARRIER                            // all A-reads done; LDS reusable

    // ---- reduce K-halves: kh=1 writes partials, kh=0 accumulates ----
    if (kh == 1) {
#pragma unroll
        for (int g = 0; g < 4; ++g)
#pragma unroll
            for (int f = 0; f < 4; ++f)
                *(floatx4*)&Rs[(wn * 64 + f * 16 + lm) * RSTR + g * 16 + lq * 4] = acc[g][f];
    }
    __syncthreads();
    if (kh == 0) {
#pragma unroll
        for (int g = 0; g < 4; ++g)
#pragma unroll
            for (int f = 0; f < 4; ++f) {
                floatx4 pp = *(const floatx4*)&Rs[(wn * 64 + f * 16 + lm) * RSTR + g * 16 + lq * 4];
#pragma unroll
                for (int r = 0; r < 4; ++r) acc[g][f][r] += pp[r];
            }
        // ---- bias (once, on the merged sums) ----
#pragma unroll
        for (int f = 0; f < 4; ++f) {
            float bb = bias[wn * 64 + f * 16 + lm];
#pragma unroll
            for (int g = 0; g < 4; ++g)
#pragma unroll
                for (int r = 0; r < 4; ++r) acc[g][f][r] += bb;
        }
        // ---- partial row norms over this wave's 64 cols ----
#pragma unroll
        for (int g = 0; g < 4; ++g) {
            float s0 = 0.f, s1 = 0.f, s2 = 0.f, s3 = 0.f;
#pragma unroll
            for (int f = 0; f < 4; ++f) {
                s0 += acc[g][f][0] * acc[g][f][0];
                s1 += acc[g][f][1] * acc[g][f][1];
                s2 += acc[g][f][2] * acc[g][f][2];
                s3 += acc[g][f][3] * acc[g][f][3];
            }
#pragma unroll
            for (int m = 1; m < 16; m <<= 1) {
                s0 += __shfl_xor(s0, m, 64);
                s1 += __shfl_xor(s1, m, 64);
                s2 += __shfl_xor(s2, m, 64);
                s3 += __shfl_xor(s3, m, 64);
            }
            if (lm == 0) {
                int rl = g * 16 + lq * 4;
                rn2[wn][rl + 0] = s0;
                rn2[wn][rl + 1] = s1;
                rn2[wn][rl + 2] = s2;
                rn2[wn][rl + 3] = s3;
            }
        }
    }
    __syncthreads();   // all Rs reads done; Zs (same memory) now safe

    // ---- Z -> LDS bf16 for GEMM2 (kh=0 waves hold the merged Z) ----
    if (kh == 0) {
#pragma unroll
        for (int g = 0; g < 4; ++g)
#pragma unroll
            for (int f = 0; f < 4; ++f) {
                int col = wn * 64 + f * 16 + lm;
#pragma unroll
                for (int r = 0; r < 4; ++r)
                    Zs[(g * 16 + lq * 4 + r) * 264 + col] = f2b(acc[g][f][r]);
            }
    }
    __syncthreads();

    // ---- GEMM2: D2[class][row] = P @ Z^T, M=112 N=64 K=256; 1 ct/wave ----
    {
        const int ct = wave;
        if (ct < 7) {
            floatx4 acc2[4];
#pragma unroll
            for (int nf = 0; nf < 4; ++nf) { acc2[nf][0]=0.f; acc2[nf][1]=0.f; acc2[nf][2]=0.f; acc2[nf][3]=0.f; }
            const unsigned short* gP = Pbf + (ct * 16 + lm) * DDIM + lq * 8;
#pragma unroll
            for (int ks = 0; ks < 8; ++ks) {
                bf16x8 ap = *(const bf16x8*)(gP + ks * 32);   // L2-hot
#pragma unroll
                for (int nf = 0; nf < 4; ++nf) {
                    bf16x8 bz = *(const bf16x8*)&Zs[(nf * 16 + lm) * 264 + ks * 32 + lq * 8];
                    acc2[nf] = __builtin_amdgcn_mfma_f32_16x16x32_bf16(ap, bz, acc2[nf], 0, 0, 0);
                }
            }
            int c0 = ct * 16 + lq * 4;
            if (c0 < CNUM) {
                floatx4 pn = *(const floatx4*)(pnorm2 + c0);
#pragma unroll
                for (int nf = 0; nf < 4; ++nf) {
                    int rl = nf * 16 + lm;
                    float rn = rn2[0][rl] + rn2[1][rl] + rn2[2][rl] + rn2[3][rl];
                    floatx4 o;
#pragma unroll
                    for (int r = 0; r < 4; ++r)
                        o[r] = (2.f * acc2[nf][r] - rn - pn[r]) * (1.f / 256.f);
                    *(floatx4*)&out[(r0 + rl) * CNUM + c0] = o;
                }
            }
        }
    }
}

extern "C" void kernel_launch(void* const* d_in, const int* in_sizes, int n_in,
                              void* d_out, int out_size, void* d_ws, size_t ws_size,
                              hipStream_t stream) {
    const float* x = (const float*)d_in[0];
    const float* W = (const float*)d_in[1];
    const float* b = (const float*)d_in[2];
    const float* P = (const float*)d_in[3];
    float* out = (float*)d_out;

    unsigned short* Wt2 = (unsigned short*)d_ws;
    unsigned short* Pbf = Wt2 + KDIM * DDIM;
    float* pn2 = (float*)(Pbf + CPAD * DDIM);

    prep<<<256 + CPAD / 4, 256, 0, stream>>>(W, P, Wt2, Pbf, pn2);
    fused_main<<<BATCH / 64, 512, 0, stream>>>(x, b, Wt2, Pbf, pn2, out);
}